// Round 1
// baseline (50631.717 us; speedup 1.0000x reference)
//
#include <hip/hip_runtime.h>
#include <stdint.h>

#define T_STEPS 4096
#define BATCH 32
#define HID 512
#define GROUPS 16           // blocks per batch
#define BLK_THREADS 512

typedef _Float16 h2_t __attribute__((ext_vector_type(2)));

__device__ inline uint32_t pack_h2(float a, float b) {
  h2_t v;
  v.x = (_Float16)a;
  v.y = (_Float16)b;
  return __builtin_bit_cast(uint32_t, v);
}

__device__ inline float fdot2(uint32_t a, uint32_t b, float c) {
  return __builtin_amdgcn_fdot2(__builtin_bit_cast(h2_t, a),
                                __builtin_bit_cast(h2_t, b), c, false);
}

__device__ inline float sigf(float x) {
  return 1.0f / (1.0f + __expf(-x));
}
__device__ inline float tanh_fast(float x) {
  float a = fabsf(x);
  float e = __expf(-2.0f * a);
  float r = (1.0f - e) / (1.0f + e);
  return copysignf(r, x);
}

// Persistent LSTM: 512 blocks = 32 batches x 16 groups; block owns 32 hidden
// units (128 gate rows). W_hh rows live in VGPRs as packed f16x2. Per step:
// all-gather h (f16, double-buffered in d_ws via LLC) -> LDS, dot2 matvec,
// ds_add cross-wave reduce, activations on 32 lanes, per-batch atomic barrier.
__global__ __launch_bounds__(BLK_THREADS, 4)
void lstm_persistent(const float* __restrict__ x0,
                     const float* __restrict__ W_ih,
                     const float* __restrict__ W_hh,
                     const float* __restrict__ b_ih,
                     const float* __restrict__ b_hh,
                     const float* __restrict__ W_lin,
                     const float* __restrict__ b_lin,
                     float* __restrict__ y,
                     uint32_t* __restrict__ h_ex,   // [2][BATCH][256] u32 (f16x2)
                     uint32_t* __restrict__ bar)    // [BATCH] stride 32 u32 (128B)
{
  __shared__ uint32_t h_lds[256];     // full h for this batch, f16x2 pairs
  __shared__ float gacc[128];         // gate accumulators (i,f,g,o x 32 units)
  __shared__ float x0_lds[T_STEPS];   // this batch's x0 column

  const int tid = threadIdx.x;
  const int g = blockIdx.x & (GROUPS - 1);   // group within batch
  const int b = blockIdx.x >> 4;             // batch
  const int u0 = g * 32;                     // first hidden unit owned
  const int wv = tid >> 6;                   // wave 0..7 -> col slice [64*wv, 64*wv+64)
  const int l  = tid & 63;                   // lane -> block-rows l and l+64

  // ---- one-time: load W_hh slice into registers as packed f16x2 ----
  uint32_t w0[32], w1[32];
  {
    const int r0 = l, r1 = l + 64;
    const int R0 = (r0 >> 5) * 512 + u0 + (r0 & 31);  // gate*512 + unit
    const int R1 = (r1 >> 5) * 512 + u0 + (r1 & 31);
    const float2* p0 = (const float2*)(W_hh + (size_t)R0 * 512 + 64 * wv);
    const float2* p1 = (const float2*)(W_hh + (size_t)R1 * 512 + 64 * wv);
#pragma unroll
    for (int k = 0; k < 32; ++k) {
      float2 a = p0[k], c = p1[k];
      w0[k] = pack_h2(a.x, a.y);
      w1[k] = pack_h2(c.x, c.y);
    }
  }
  // ---- one-time: stage this batch's x0 column into LDS ----
  for (int i = tid; i < T_STEPS; i += BLK_THREADS) x0_lds[i] = x0[i * BATCH + b];

  // ---- activation-lane state (lanes 0..31 of wave 0) ----
  float c_state = 0.f;
  float wih[4] = {0.f, 0.f, 0.f, 0.f}, bsum[4] = {0.f, 0.f, 0.f, 0.f};
  float wlin_u = 0.f, blin = 0.f;
  if (tid < 32) {
#pragma unroll
    for (int j = 0; j < 4; ++j) {
      int R = j * 512 + u0 + tid;
      wih[j] = W_ih[R];
      bsum[j] = b_ih[R] + b_hh[R];
    }
    wlin_u = W_lin[u0 + tid];
    blin = b_lin[0];
  }

  uint32_t* bar_b = bar + b * 32;

  for (int t = 0; t < T_STEPS; ++t) {
    // ---- wait for all 16 blocks of this batch to have finished step t-1 ----
    if (t > 0) {
      if (tid == 0) {
        const uint32_t target = (uint32_t)(GROUPS * t);
        int guard = 0;
        while (__hip_atomic_load(bar_b, __ATOMIC_ACQUIRE,
                                 __HIP_MEMORY_SCOPE_AGENT) < target) {
          if (++guard > (1 << 24)) break;  // safety: wrong answer beats a hang
        }
      }
      __syncthreads();
    }
    // ---- stage full h (f16x2) into LDS; zero gate accumulators ----
    {
      const uint32_t* h_src =
          h_ex + (size_t)(t & 1) * (BATCH * 256) + (size_t)b * 256;
      if (tid < 256) {
        h_lds[tid] = __hip_atomic_load((uint32_t*)(h_src + tid),
                                       __ATOMIC_RELAXED,
                                       __HIP_MEMORY_SCOPE_AGENT);
      } else if (tid < 384) {
        gacc[tid - 256] = 0.f;
      }
    }
    __syncthreads();

    // ---- matvec: 2 rows x 64 cols per lane, f16 dot2, fp32 accumulate ----
    float acc0 = 0.f, acc1 = 0.f;
    const uint4* hp = (const uint4*)(h_lds + 32 * wv);  // wave-uniform broadcast
#pragma unroll
    for (int cch = 0; cch < 2; ++cch) {
      uint4 h4[4];
#pragma unroll
      for (int q = 0; q < 4; ++q) h4[q] = hp[4 * cch + q];
#pragma unroll
      for (int q = 0; q < 4; ++q) {
        const int k = 16 * cch + 4 * q;
        acc0 = fdot2(w0[k + 0], h4[q].x, acc0); acc1 = fdot2(w1[k + 0], h4[q].x, acc1);
        acc0 = fdot2(w0[k + 1], h4[q].y, acc0); acc1 = fdot2(w1[k + 1], h4[q].y, acc1);
        acc0 = fdot2(w0[k + 2], h4[q].z, acc0); acc1 = fdot2(w1[k + 2], h4[q].z, acc1);
        acc0 = fdot2(w0[k + 3], h4[q].w, acc0); acc1 = fdot2(w1[k + 3], h4[q].w, acc1);
      }
    }
    atomicAdd(&gacc[l], acc0);        // banks l%32: 2-way, conflict-free
    atomicAdd(&gacc[l + 64], acc1);
    __syncthreads();

    // ---- activations + state update + output + h publish + arrive ----
    if (tid < 32) {
      const float xv = x0_lds[t];
      float gi = gacc[tid]      + xv * wih[0] + bsum[0];
      float gf = gacc[tid + 32] + xv * wih[1] + bsum[1];
      float gg = gacc[tid + 64] + xv * wih[2] + bsum[2];
      float go = gacc[tid + 96] + xv * wih[3] + bsum[3];
      float si = sigf(gi), sf = sigf(gf), tg = tanh_fast(gg), so = sigf(go);
      c_state = sf * c_state + si * tg;
      float h = so * tanh_fast(c_state);

      // partial y = sum over owned units of W_lin[u]*h[u]
      float p = wlin_u * h;
#pragma unroll
      for (int m = 16; m >= 1; m >>= 1) p += __shfl_xor(p, m, 64);

      // publish h slice (f16x2) to next step's buffer
      float hn = __shfl_down(h, 1, 64);
      if ((tid & 1) == 0) {
        uint32_t hp2 = pack_h2(h, hn);
        uint32_t* dst = h_ex + (size_t)((t + 1) & 1) * (BATCH * 256) +
                        (size_t)b * 256 + 16 * g + (tid >> 1);
        __hip_atomic_store(dst, hp2, __ATOMIC_RELAXED, __HIP_MEMORY_SCOPE_AGENT);
      }
      if (tid == 0) {
        if (g == 0) p += blin + xv;           // bias + residual, added once
        unsafeAtomicAdd(&y[t * BATCH + b], p);
        // release orders this wave's h stores (vmcnt drain) before the arrive
        __hip_atomic_fetch_add(bar_b, 1u, __ATOMIC_RELEASE,
                               __HIP_MEMORY_SCOPE_AGENT);
      }
    }
  }
}

extern "C" void kernel_launch(void* const* d_in, const int* in_sizes, int n_in,
                              void* d_out, int out_size, void* d_ws, size_t ws_size,
                              hipStream_t stream) {
  const float* x0    = (const float*)d_in[0];
  const float* W_ih  = (const float*)d_in[1];
  const float* W_hh  = (const float*)d_in[2];
  const float* b_ih  = (const float*)d_in[3];
  const float* b_hh  = (const float*)d_in[4];
  const float* W_lin = (const float*)d_in[5];
  const float* b_lin = (const float*)d_in[6];
  float* y = (float*)d_out;

  uint32_t* h_ex = (uint32_t*)d_ws;                       // 2*32*256 u32 = 64 KB
  uint32_t* bar  = (uint32_t*)((char*)d_ws + 2 * BATCH * 256 * sizeof(uint32_t));
  const size_t init_bytes = 2 * BATCH * 256 * sizeof(uint32_t) + BATCH * 128;

  hipMemsetAsync(d_ws, 0, init_bytes, stream);                     // h0=0, bar=0
  hipMemsetAsync(d_out, 0, (size_t)out_size * sizeof(float), stream);  // y accum base

  hipLaunchKernelGGL(lstm_persistent, dim3(BATCH * GROUPS), dim3(BLK_THREADS),
                     0, stream,
                     x0, W_ih, W_hh, b_ih, b_hh, W_lin, b_lin, y, h_ex, bar);
}

// Round 2
// 29979.156 us; speedup vs baseline: 1.6889x; 1.6889x over previous
//
#include <hip/hip_runtime.h>
#include <stdint.h>

#define T_STEPS 4096
#define BATCH 32
#define HID 512
#define GROUPS 16           // blocks per batch
#define BLK_THREADS 512

typedef _Float16 h2_t __attribute__((ext_vector_type(2)));

__device__ inline uint32_t pack_h2(float a, float b) {
  h2_t v;
  v.x = (_Float16)a;
  v.y = (_Float16)b;
  return __builtin_bit_cast(uint32_t, v);
}

__device__ inline float fdot2(uint32_t a, uint32_t b, float c) {
  return __builtin_amdgcn_fdot2(__builtin_bit_cast(h2_t, a),
                                __builtin_bit_cast(h2_t, b), c, false);
}

__device__ inline float sigf(float x) {
  return 1.0f / (1.0f + __expf(-x));
}
__device__ inline float tanh_fast(float x) {
  float a = fabsf(x);
  float e = __expf(-2.0f * a);
  float r = (1.0f - e) / (1.0f + e);
  return copysignf(r, x);
}

// Persistent LSTM: 512 blocks = 32 batches x 16 groups; block owns 32 hidden
// units (128 gate rows). W_hh rows pinned in VGPRs as packed f16x2 (asm reg
// pin prevents the compiler rematerializing the loads inside the t-loop —
// round-1 failure mode: VGPR_Count=64, 803 MB FETCH_SIZE from per-step W_hh
// re-reads). Per step: all-gather h (f16, double-buffered in d_ws via LLC,
// sc1 cache-bypassing loads) -> LDS, dot2 matvec, LDS-atomic cross-wave
// reduce, activations on 32 lanes, per-batch atomic barrier (RELAXED spin;
// producer's RELEASE fetch_add orders the h stores).
__global__ __launch_bounds__(BLK_THREADS, 4)
void lstm_persistent(const float* __restrict__ x0,
                     const float* __restrict__ W_ih,
                     const float* __restrict__ W_hh,
                     const float* __restrict__ b_ih,
                     const float* __restrict__ b_hh,
                     const float* __restrict__ W_lin,
                     const float* __restrict__ b_lin,
                     float* __restrict__ y,
                     uint32_t* __restrict__ h_ex,   // [2][BATCH][256] u32 (f16x2)
                     uint32_t* __restrict__ bar)    // [BATCH] stride 32 u32 (128B)
{
  __shared__ uint32_t h_lds[256];     // full h for this batch, f16x2 pairs
  __shared__ float gacc[128];         // gate accumulators (i,f,g,o x 32 units)
  __shared__ float x0_lds[T_STEPS];   // this batch's x0 column

  const int tid = threadIdx.x;
  const int g = blockIdx.x & (GROUPS - 1);   // group within batch
  const int b = blockIdx.x >> 4;             // batch
  const int u0 = g * 32;                     // first hidden unit owned
  const int wv = tid >> 6;                   // wave 0..7 -> col slice [64*wv, 64*wv+64)
  const int l  = tid & 63;                   // lane -> block-rows l and l+64

  // ---- one-time: load W_hh slice into registers as packed f16x2 ----
  uint32_t w0[32], w1[32];
  {
    const int r0 = l, r1 = l + 64;
    const int R0 = (r0 >> 5) * 512 + u0 + (r0 & 31);  // gate*512 + unit
    const int R1 = (r1 >> 5) * 512 + u0 + (r1 & 31);
    const float2* p0 = (const float2*)(W_hh + (size_t)R0 * 512 + 64 * wv);
    const float2* p1 = (const float2*)(W_hh + (size_t)R1 * 512 + 64 * wv);
#pragma unroll
    for (int k = 0; k < 32; ++k) {
      float2 a = p0[k], c = p1[k];
      w0[k] = pack_h2(a.x, a.y);
      w1[k] = pack_h2(c.x, c.y);
    }
    // Pin the packed weights into VGPRs: asm outputs cannot be
    // rematerialized, so they stay live across the whole t-loop instead of
    // being re-loaded from global memory each step.
#pragma unroll
    for (int k = 0; k < 32; ++k) {
      asm("" : "+v"(w0[k]), "+v"(w1[k]));
    }
  }
  // ---- one-time: stage this batch's x0 column into LDS ----
  for (int i = tid; i < T_STEPS; i += BLK_THREADS) x0_lds[i] = x0[i * BATCH + b];

  // ---- activation-lane state (lanes 0..31 of wave 0) ----
  float c_state = 0.f;
  float wih[4] = {0.f, 0.f, 0.f, 0.f}, bsum[4] = {0.f, 0.f, 0.f, 0.f};
  float wlin_u = 0.f, blin = 0.f;
  if (tid < 32) {
#pragma unroll
    for (int j = 0; j < 4; ++j) {
      int R = j * 512 + u0 + tid;
      wih[j] = W_ih[R];
      bsum[j] = b_ih[R] + b_hh[R];
    }
    wlin_u = W_lin[u0 + tid];
    blin = b_lin[0];
  }

  uint32_t* bar_b = bar + b * 32;

  for (int t = 0; t < T_STEPS; ++t) {
    // ---- wait for all 16 blocks of this batch to have finished step t-1 ----
    if (t > 0) {
      if (tid == 0) {
        const uint32_t target = (uint32_t)(GROUPS * t);
        int guard = 0;
        // RELAXED spin: agent-scope load bypasses L1 so it sees the update;
        // no per-poll acquire (which would invalidate caches every
        // iteration). Ordering comes from the producer's RELEASE fetch_add:
        // once the counter reads `target`, the released h stores are at the
        // coherence point, and our h reads below are sc1 (cache-bypassing).
        while (__hip_atomic_load(bar_b, __ATOMIC_RELAXED,
                                 __HIP_MEMORY_SCOPE_AGENT) < target) {
          if (++guard > (1 << 24)) break;  // safety: wrong answer beats a hang
        }
      }
      __syncthreads();
    }
    // ---- stage full h (f16x2) into LDS; zero gate accumulators ----
    {
      const uint32_t* h_src =
          h_ex + (size_t)(t & 1) * (BATCH * 256) + (size_t)b * 256;
      if (tid < 256) {
        h_lds[tid] = __hip_atomic_load((uint32_t*)(h_src + tid),
                                       __ATOMIC_RELAXED,
                                       __HIP_MEMORY_SCOPE_AGENT);
      } else if (tid < 384) {
        gacc[tid - 256] = 0.f;
      }
    }
    __syncthreads();

    // ---- matvec: 2 rows x 64 cols per lane, f16 dot2, fp32 accumulate ----
    float acc0 = 0.f, acc1 = 0.f;
    const uint4* hp = (const uint4*)(h_lds + 32 * wv);  // wave-uniform broadcast
#pragma unroll
    for (int cch = 0; cch < 2; ++cch) {
      uint4 h4[4];
#pragma unroll
      for (int q = 0; q < 4; ++q) h4[q] = hp[4 * cch + q];
#pragma unroll
      for (int q = 0; q < 4; ++q) {
        const int k = 16 * cch + 4 * q;
        acc0 = fdot2(w0[k + 0], h4[q].x, acc0); acc1 = fdot2(w1[k + 0], h4[q].x, acc1);
        acc0 = fdot2(w0[k + 1], h4[q].y, acc0); acc1 = fdot2(w1[k + 1], h4[q].y, acc1);
        acc0 = fdot2(w0[k + 2], h4[q].z, acc0); acc1 = fdot2(w1[k + 2], h4[q].z, acc1);
        acc0 = fdot2(w0[k + 3], h4[q].w, acc0); acc1 = fdot2(w1[k + 3], h4[q].w, acc1);
      }
    }
    atomicAdd(&gacc[l], acc0);        // banks l%32: 2-way, conflict-free
    atomicAdd(&gacc[l + 64], acc1);
    __syncthreads();

    // ---- activations + state update + output + h publish + arrive ----
    if (tid < 32) {
      const float xv = x0_lds[t];
      float gi = gacc[tid]      + xv * wih[0] + bsum[0];
      float gf = gacc[tid + 32] + xv * wih[1] + bsum[1];
      float gg = gacc[tid + 64] + xv * wih[2] + bsum[2];
      float go = gacc[tid + 96] + xv * wih[3] + bsum[3];
      float si = sigf(gi), sf = sigf(gf), tg = tanh_fast(gg), so = sigf(go);
      c_state = sf * c_state + si * tg;
      float h = so * tanh_fast(c_state);

      // partial y = sum over owned units of W_lin[u]*h[u]
      float p = wlin_u * h;
#pragma unroll
      for (int m = 16; m >= 1; m >>= 1) p += __shfl_xor(p, m, 64);

      // publish h slice (f16x2) to next step's buffer
      float hn = __shfl_down(h, 1, 64);
      if ((tid & 1) == 0) {
        uint32_t hp2 = pack_h2(h, hn);
        uint32_t* dst = h_ex + (size_t)((t + 1) & 1) * (BATCH * 256) +
                        (size_t)b * 256 + 16 * g + (tid >> 1);
        __hip_atomic_store(dst, hp2, __ATOMIC_RELAXED, __HIP_MEMORY_SCOPE_AGENT);
      }
      if (tid == 0) {
        if (g == 0) p += blin + xv;           // bias + residual, added once
        unsafeAtomicAdd(&y[t * BATCH + b], p);
        // release orders this wave's h stores (vmcnt drain) before the arrive
        __hip_atomic_fetch_add(bar_b, 1u, __ATOMIC_RELEASE,
                               __HIP_MEMORY_SCOPE_AGENT);
      }
    }
  }
}

extern "C" void kernel_launch(void* const* d_in, const int* in_sizes, int n_in,
                              void* d_out, int out_size, void* d_ws, size_t ws_size,
                              hipStream_t stream) {
  const float* x0    = (const float*)d_in[0];
  const float* W_ih  = (const float*)d_in[1];
  const float* W_hh  = (const float*)d_in[2];
  const float* b_ih  = (const float*)d_in[3];
  const float* b_hh  = (const float*)d_in[4];
  const float* W_lin = (const float*)d_in[5];
  const float* b_lin = (const float*)d_in[6];
  float* y = (float*)d_out;

  uint32_t* h_ex = (uint32_t*)d_ws;                       // 2*32*256 u32 = 64 KB
  uint32_t* bar  = (uint32_t*)((char*)d_ws + 2 * BATCH * 256 * sizeof(uint32_t));
  const size_t init_bytes = 2 * BATCH * 256 * sizeof(uint32_t) + BATCH * 128;

  hipMemsetAsync(d_ws, 0, init_bytes, stream);                     // h0=0, bar=0
  hipMemsetAsync(d_out, 0, (size_t)out_size * sizeof(float), stream);  // y accum base

  hipLaunchKernelGGL(lstm_persistent, dim3(BATCH * GROUPS), dim3(BLK_THREADS),
                     0, stream,
                     x0, W_ih, W_hh, b_ih, b_hh, W_lin, b_lin, y, h_ex, bar);
}

// Round 3
// 24447.124 us; speedup vs baseline: 2.0711x; 1.2263x over previous
//
#include <hip/hip_runtime.h>
#include <stdint.h>

#define T_STEPS 4096
#define BATCH 32
#define HID 512
#define GROUPS 16           // blocks per batch
#define BLK_THREADS 512

typedef _Float16 h2_t __attribute__((ext_vector_type(2)));

__device__ inline uint32_t pack_h2(float a, float b) {
  h2_t v;
  v.x = (_Float16)a;
  v.y = (_Float16)b;
  return __builtin_bit_cast(uint32_t, v);
}

__device__ inline float fdot2(uint32_t a, uint32_t b, float c) {
  return __builtin_amdgcn_fdot2(__builtin_bit_cast(h2_t, a),
                                __builtin_bit_cast(h2_t, b), c, false);
}

// AGPR-resident weight read: value lives in the accumulator file for the
// whole kernel (unified VGPR/AGPR RF on gfx950); one VALU op to fetch.
// NOT volatile: scheduler is free to interleave with fdot2.
__device__ inline uint32_t aread(uint32_t a) {
  uint32_t v;
  asm("v_accvgpr_read_b32 %0, %1" : "=v"(v) : "a"(a));
  return v;
}

__device__ inline float sigf(float x) {
  return 1.0f / (1.0f + __expf(-x));
}
__device__ inline float tanh_fast(float x) {
  float a = fabsf(x);
  float e = __expf(-2.0f * a);
  float r = (1.0f - e) / (1.0f + e);
  return copysignf(r, x);
}

// Persistent LSTM: 512 blocks = 32 batches x 16 groups; block owns 32 hidden
// units (128 gate rows). W_hh packed f16x2 pinned in AGPRs (explicit
// v_accvgpr_write; round-2 evidence: compiler would not keep them in arch
// VGPRs). Per step: poll 16 per-group tags (one 64B line, one coalesced load,
// __all), sc1-load h into LDS, dot2 matvec, LDS-atomic reduce, activations on
// 32 lanes, publish h slice (sc1) -> s_waitcnt vmcnt(0) -> relaxed tag store.
// NO acquire/release anywhere: agent-scope CMOs (buffer_wbl2/buffer_inv) per
// step were the round-2 latency suspect; all cross-block data is sc1 so the
// IF$ is the single coherence point and manual vmcnt(0) ordering suffices.
__global__ __launch_bounds__(BLK_THREADS, 4)
void lstm_persistent(const float* __restrict__ x0,
                     const float* __restrict__ W_ih,
                     const float* __restrict__ W_hh,
                     const float* __restrict__ b_ih,
                     const float* __restrict__ b_hh,
                     const float* __restrict__ W_lin,
                     const float* __restrict__ b_lin,
                     float* __restrict__ y,
                     uint32_t* __restrict__ h_ex,   // [2][BATCH][256] u32 (f16x2)
                     uint32_t* __restrict__ tags)   // [BATCH][16] u32, 64B/batch
{
  __shared__ uint32_t h_lds[256];     // full h for this batch, f16x2 pairs
  __shared__ float gacc[128];         // gate accumulators (i,f,g,o x 32 units)
  __shared__ float x0_lds[T_STEPS];   // this batch's x0 column

  const int tid = threadIdx.x;
  const int g = blockIdx.x & (GROUPS - 1);   // group within batch
  const int b = blockIdx.x >> 4;             // batch
  const int u0 = g * 32;                     // first hidden unit owned
  const int wv = tid >> 6;                   // wave 0..7 -> col slice [64*wv, 64*wv+64)
  const int l  = tid & 63;                   // lane -> block-rows l and l+64

  // ---- one-time: load W_hh slice, pack f16x2, park in AGPRs ----
  uint32_t a0[32], a1[32];
  {
    const int r0 = l, r1 = l + 64;
    const int R0 = (r0 >> 5) * 512 + u0 + (r0 & 31);  // gate*512 + unit
    const int R1 = (r1 >> 5) * 512 + u0 + (r1 & 31);
    const float2* p0 = (const float2*)(W_hh + (size_t)R0 * 512 + 64 * wv);
    const float2* p1 = (const float2*)(W_hh + (size_t)R1 * 512 + 64 * wv);
#pragma unroll
    for (int k = 0; k < 32; ++k) {
      float2 a = p0[k], c = p1[k];
      uint32_t t0 = pack_h2(a.x, a.y);
      uint32_t t1 = pack_h2(c.x, c.y);
      asm("v_accvgpr_write_b32 %0, %1" : "=a"(a0[k]) : "v"(t0));
      asm("v_accvgpr_write_b32 %0, %1" : "=a"(a1[k]) : "v"(t1));
    }
  }
  // ---- one-time: stage this batch's x0 column into LDS ----
  for (int i = tid; i < T_STEPS; i += BLK_THREADS) x0_lds[i] = x0[i * BATCH + b];

  // ---- activation-lane state (lanes 0..31 of wave 0) ----
  float c_state = 0.f;
  float wih[4] = {0.f, 0.f, 0.f, 0.f}, bsum[4] = {0.f, 0.f, 0.f, 0.f};
  float wlin_u = 0.f, blin = 0.f;
  if (tid < 32) {
#pragma unroll
    for (int j = 0; j < 4; ++j) {
      int R = j * 512 + u0 + tid;
      wih[j] = W_ih[R];
      bsum[j] = b_ih[R] + b_hh[R];
    }
    wlin_u = W_lin[u0 + tid];
    blin = b_lin[0];
  }

  uint32_t* tags_b = tags + b * 16;   // one 64B line per batch

  for (int t = 0; t < T_STEPS; ++t) {
    // ---- wait: all 16 groups of this batch published step t-1 ----
    // Wave 0 polls the 16 tags with a single coalesced 64B load; relaxed
    // (sc1, IF$-served) — no acquire CMO. s_sleep backs off TCC pressure.
    if (t > 0) {
      if (tid < 64) {
        const uint32_t target = (uint32_t)t;
        uint32_t* tp = tags_b + (tid & 15);
        int guard = 0;
        for (;;) {
          uint32_t v = __hip_atomic_load(tp, __ATOMIC_RELAXED,
                                         __HIP_MEMORY_SCOPE_AGENT);
          if (__all((int)(v >= target))) break;
          if (++guard > (1 << 22)) break;  // safety: wrong answer beats a hang
          __builtin_amdgcn_s_sleep(1);
        }
      }
      __syncthreads();
    }
    // ---- stage full h (f16x2) into LDS; zero gate accumulators ----
    {
      const uint32_t* h_src =
          h_ex + (size_t)(t & 1) * (BATCH * 256) + (size_t)b * 256;
      if (tid < 256) {
        h_lds[tid] = __hip_atomic_load((uint32_t*)(h_src + tid),
                                       __ATOMIC_RELAXED,
                                       __HIP_MEMORY_SCOPE_AGENT);
      } else if (tid < 384) {
        gacc[tid - 256] = 0.f;
      }
    }
    __syncthreads();

    // ---- matvec: 2 rows x 64 cols per lane, f16 dot2, fp32 accumulate ----
    float acc0 = 0.f, acc1 = 0.f;
    const uint4* hp = (const uint4*)(h_lds + 32 * wv);  // wave-uniform broadcast
#pragma unroll
    for (int q = 0; q < 8; ++q) {
      uint4 h4 = hp[q];
      const int k = 4 * q;
      acc0 = fdot2(aread(a0[k + 0]), h4.x, acc0); acc1 = fdot2(aread(a1[k + 0]), h4.x, acc1);
      acc0 = fdot2(aread(a0[k + 1]), h4.y, acc0); acc1 = fdot2(aread(a1[k + 1]), h4.y, acc1);
      acc0 = fdot2(aread(a0[k + 2]), h4.z, acc0); acc1 = fdot2(aread(a1[k + 2]), h4.z, acc1);
      acc0 = fdot2(aread(a0[k + 3]), h4.w, acc0); acc1 = fdot2(aread(a1[k + 3]), h4.w, acc1);
    }
    atomicAdd(&gacc[l], acc0);        // banks l%32: 2-way, conflict-free
    atomicAdd(&gacc[l + 64], acc1);
    __syncthreads();

    // ---- activations + state update + output + h publish + tag ----
    if (tid < 32) {
      const float xv = x0_lds[t];
      float gi = gacc[tid]      + xv * wih[0] + bsum[0];
      float gf = gacc[tid + 32] + xv * wih[1] + bsum[1];
      float gg = gacc[tid + 64] + xv * wih[2] + bsum[2];
      float go = gacc[tid + 96] + xv * wih[3] + bsum[3];
      float si = sigf(gi), sf = sigf(gf), tg = tanh_fast(gg), so = sigf(go);
      c_state = sf * c_state + si * tg;
      float h = so * tanh_fast(c_state);

      // partial y = sum over owned units of W_lin[u]*h[u]
      float p = wlin_u * h;
#pragma unroll
      for (int m = 16; m >= 1; m >>= 1) p += __shfl_xor(p, m, 64);

      // publish h slice (f16x2, sc1) to next step's buffer: 16 lanes, one
      // coalesced 64B store
      float hn = __shfl_down(h, 1, 64);
      if ((tid & 1) == 0) {
        uint32_t hp2 = pack_h2(h, hn);
        uint32_t* dst = h_ex + (size_t)((t + 1) & 1) * (BATCH * 256) +
                        (size_t)b * 256 + 16 * g + (tid >> 1);
        __hip_atomic_store(dst, hp2, __ATOMIC_RELAXED, __HIP_MEMORY_SCOPE_AGENT);
      }
      // manual release: drain the data stores, then plain relaxed tag store.
      // (wave-level s_waitcnt — scalar instr, wave0 only reaches here)
      asm volatile("s_waitcnt vmcnt(0)" ::: "memory");
      if (tid == 0) {
        __hip_atomic_store(tags_b + g, (uint32_t)(t + 1), __ATOMIC_RELAXED,
                           __HIP_MEMORY_SCOPE_AGENT);
        if (g == 0) p += blin + xv;           // bias + residual, added once
        unsafeAtomicAdd(&y[t * BATCH + b], p);
      }
    }
  }
}

extern "C" void kernel_launch(void* const* d_in, const int* in_sizes, int n_in,
                              void* d_out, int out_size, void* d_ws, size_t ws_size,
                              hipStream_t stream) {
  const float* x0    = (const float*)d_in[0];
  const float* W_ih  = (const float*)d_in[1];
  const float* W_hh  = (const float*)d_in[2];
  const float* b_ih  = (const float*)d_in[3];
  const float* b_hh  = (const float*)d_in[4];
  const float* W_lin = (const float*)d_in[5];
  const float* b_lin = (const float*)d_in[6];
  float* y = (float*)d_out;

  uint32_t* h_ex = (uint32_t*)d_ws;                       // 2*32*256 u32 = 64 KB
  uint32_t* tags = (uint32_t*)((char*)d_ws + 2 * BATCH * 256 * sizeof(uint32_t));
  const size_t init_bytes =
      2 * BATCH * 256 * sizeof(uint32_t) + BATCH * 16 * sizeof(uint32_t);

  hipMemsetAsync(d_ws, 0, init_bytes, stream);                     // h0=0, tags=0
  hipMemsetAsync(d_out, 0, (size_t)out_size * sizeof(float), stream);  // y accum base

  hipLaunchKernelGGL(lstm_persistent, dim3(BATCH * GROUPS), dim3(BLK_THREADS),
                     0, stream,
                     x0, W_ih, W_hh, b_ih, b_hh, W_lin, b_lin, y, h_ex, tags);
}

// Round 4
// 16811.586 us; speedup vs baseline: 3.0117x; 1.4542x over previous
//
#include <hip/hip_runtime.h>
#include <stdint.h>

#define T_STEPS 4096
#define BATCH 32
#define HID 512
#define GROUPS 8            // blocks per batch
#define BLK_THREADS 1024    // 16 waves; 256 blocks total = 1 block/CU

typedef _Float16 h2_t __attribute__((ext_vector_type(2)));

__device__ inline uint32_t pack_h2(float a, float b) {
  h2_t v;
  v.x = (_Float16)a;
  v.y = (_Float16)b;
  return __builtin_bit_cast(uint32_t, v);
}

__device__ inline float fdot2(uint32_t a, uint32_t b, float c) {
  return __builtin_amdgcn_fdot2(__builtin_bit_cast(h2_t, a),
                                __builtin_bit_cast(h2_t, b), c, false);
}

// AGPR-resident weight read (unified VGPR/AGPR RF on gfx950). Proven in
// round 3 to keep W_hh on-chip (FETCH_SIZE unchanged vs round 2 => no
// per-step weight re-fetch).
__device__ inline uint32_t aread(uint32_t a) {
  uint32_t v;
  asm("v_accvgpr_read_b32 %0, %1" : "=v"(v) : "a"(a));
  return v;
}

__device__ inline float sigf(float x) {
  return 1.0f / (1.0f + __expf(-x));
}
__device__ inline float tanh_fast(float x) {
  float a = fabsf(x);
  float e = __expf(-2.0f * a);
  float r = (1.0f - e) / (1.0f + e);
  return copysignf(r, x);
}

// Persistent LSTM, round 4: 256 blocks = 32 batches x 8 groups, 1024 thr,
// EXACTLY 1 block/CU (decouples batches — round-3 counters showed 2.7x
// run-to-run variance from cross-batch CU sharing + barrier coupling).
//
// h exchange is SELF-VALIDATING: each dword = (step_tag<<16)|f16(h), double
// buffered by step parity. Consumers poll the data itself (one 256B
// coalesced load per wave of exactly the column slice that wave needs);
// tag-match implies the value is valid — no separate tag line, no producer
// vmcnt drain, no dependent second hop, no acquire/release CMOs. Word
// atomicity of a 32-bit load makes this ordering-free.
//
// Per wave per step: poll own slice -> wave-local LDS transpose (even lanes
// pack f16x2; 8x ds_read_b128 uniform) -> 64 fdot2 vs AGPR weights -> LDS
// atomic reduce into parity-buffered gacc -> ONE __syncthreads -> wave 0
// lanes 0..63 do activations, publish tagged h, y-reduction.
__global__ __launch_bounds__(BLK_THREADS, 4)
void lstm_persistent(const float* __restrict__ x0,
                     const float* __restrict__ W_ih,
                     const float* __restrict__ W_hh,
                     const float* __restrict__ b_ih,
                     const float* __restrict__ b_hh,
                     const float* __restrict__ W_lin,
                     const float* __restrict__ b_lin,
                     float* __restrict__ y,
                     uint32_t* __restrict__ h_ex)   // [2][BATCH][512] tagged f16
{
  __shared__ float x0_lds[T_STEPS];     // this batch's x0 column (16 KB)
  __shared__ uint32_t trans[16][32];    // per-wave f16x2 transpose (2 KB)
  __shared__ float gacc[2][256];        // parity-buffered gate accumulators

  const int tid = threadIdx.x;
  // XCD-grouped mapping (round-robin blockIdx->XCD assumed, perf-only):
  // all 8 groups of a batch land on one XCD if the round-robin holds.
  const int xcd = blockIdx.x & 7;
  const int s   = blockIdx.x >> 3;           // 0..31
  const int g   = s & 7;                     // group within batch
  const int b   = xcd + 8 * (s >> 3);        // batch
  const int u0  = g * 64;                    // first hidden unit owned
  const int wv  = tid >> 6;                  // wave 0..15
  const int rg  = wv >> 3;                   // row-group 0..1 (128 rows each)
  const int cs  = wv & 7;                    // col-slice 0..7 (64 cols each)
  const int l   = tid & 63;

  // ---- one-time: load W_hh slice, pack f16x2, park in AGPRs ----
  uint32_t a0[32], a1[32];
  {
    const int r0 = 128 * rg + l;             // block-local gate-row
    const int r1 = r0 + 64;
    const int R0 = (r0 >> 6) * HID + u0 + (r0 & 63);  // gate*512 + unit
    const int R1 = (r1 >> 6) * HID + u0 + (r1 & 63);
    const float2* p0 = (const float2*)(W_hh + (size_t)R0 * HID + 64 * cs);
    const float2* p1 = (const float2*)(W_hh + (size_t)R1 * HID + 64 * cs);
#pragma unroll
    for (int k = 0; k < 32; ++k) {
      float2 a = p0[k], c = p1[k];
      uint32_t t0 = pack_h2(a.x, a.y);
      uint32_t t1 = pack_h2(c.x, c.y);
      asm("v_accvgpr_write_b32 %0, %1" : "=a"(a0[k]) : "v"(t0));
      asm("v_accvgpr_write_b32 %0, %1" : "=a"(a1[k]) : "v"(t1));
    }
  }
  // ---- one-time: stage this batch's x0 column; zero gacc ----
  for (int i = tid; i < T_STEPS; i += BLK_THREADS) x0_lds[i] = x0[i * BATCH + b];
  if (tid < 256) { gacc[0][tid] = 0.f; gacc[1][tid] = 0.f; }

  // ---- activation-lane state (lanes 0..63 of wave 0) ----
  float c_state = 0.f;
  float wih[4] = {0.f, 0.f, 0.f, 0.f}, bsum[4] = {0.f, 0.f, 0.f, 0.f};
  float wlin_u = 0.f, blin = 0.f;
  if (tid < 64) {
#pragma unroll
    for (int j = 0; j < 4; ++j) {
      int R = j * HID + u0 + tid;
      wih[j] = W_ih[R];
      bsum[j] = b_ih[R] + b_hh[R];
    }
    wlin_u = W_lin[u0 + tid];
    blin = b_lin[0];
  }
  __syncthreads();

  for (int t = 0; t < T_STEPS; ++t) {
    const int sl = t & 1, ns = sl ^ 1;

    // ---- poll own column slice; tag-match == data valid ----
    const uint32_t* src =
        h_ex + ((size_t)sl * BATCH + b) * 512 + 64 * cs + l;
    uint32_t v;
    {
      const uint32_t tag = (uint32_t)t;
      int guard = 0;
      for (;;) {
        v = __hip_atomic_load(src, __ATOMIC_RELAXED,
                              __HIP_MEMORY_SCOPE_AGENT);
        if (__all((int)((v >> 16) == tag))) break;
        if (++guard > (1 << 20)) break;  // safety: wrong answer beats a hang
        __builtin_amdgcn_s_sleep(1);
      }
    }

    // Zero the OTHER gacc slot for step t+1. Safe: passing the poll implies
    // our own activation wave published h_t, which implies it already read
    // gacc[ns] (step t-1's sums). Barrier below orders it vs next step.
    if (l < 16) gacc[ns][wv * 16 + l] = 0.f;

    // ---- wave-local transpose: tagged dwords -> packed f16x2 pairs ----
    {
      uint32_t nv = __shfl_down(v, 1, 64);
      if ((l & 1) == 0) trans[wv][l >> 1] = (v & 0xffffu) | (nv << 16);
    }
    // ---- matvec: 2 rows x 64 cols per lane, fp32 accumulate ----
    float acc0 = 0.f, acc1 = 0.f;
    const uint4* hp = (const uint4*)trans[wv];   // wave-uniform broadcast
#pragma unroll
    for (int q = 0; q < 8; ++q) {
      uint4 h4 = hp[q];
      const int k = 4 * q;
      acc0 = fdot2(aread(a0[k + 0]), h4.x, acc0); acc1 = fdot2(aread(a1[k + 0]), h4.x, acc1);
      acc0 = fdot2(aread(a0[k + 1]), h4.y, acc0); acc1 = fdot2(aread(a1[k + 1]), h4.y, acc1);
      acc0 = fdot2(aread(a0[k + 2]), h4.z, acc0); acc1 = fdot2(aread(a1[k + 2]), h4.z, acc1);
      acc0 = fdot2(aread(a0[k + 3]), h4.w, acc0); acc1 = fdot2(aread(a1[k + 3]), h4.w, acc1);
    }
    atomicAdd(&gacc[sl][128 * rg + l], acc0);       // 2-way bank, conflict-free
    atomicAdd(&gacc[sl][128 * rg + 64 + l], acc1);
    __syncthreads();   // the ONE block barrier per step

    // ---- activations + publish + y (wave 0, 64 lanes = 64 owned units) ----
    if (tid < 64) {
      const float xv = x0_lds[t];
      float gi = gacc[sl][tid]       + xv * wih[0] + bsum[0];
      float gf = gacc[sl][tid + 64]  + xv * wih[1] + bsum[1];
      float gg = gacc[sl][tid + 128] + xv * wih[2] + bsum[2];
      float go = gacc[sl][tid + 192] + xv * wih[3] + bsum[3];
      float si = sigf(gi), sf = sigf(gf), tg = tanh_fast(gg), so = sigf(go);
      c_state = sf * c_state + si * tg;
      float h = so * tanh_fast(c_state);

      // publish FIRST (critical path): tagged dword, no drain needed
      uint16_t hb = __builtin_bit_cast(uint16_t, (_Float16)h);
      uint32_t tagged = ((uint32_t)(t + 1) << 16) | (uint32_t)hb;
      uint32_t* dst = h_ex + ((size_t)ns * BATCH + b) * 512 + u0 + tid;
      __hip_atomic_store(dst, tagged, __ATOMIC_RELAXED,
                         __HIP_MEMORY_SCOPE_AGENT);

      // y[t] partial: sum over owned units of W_lin[u]*h[u]
      float p = wlin_u * h;
#pragma unroll
      for (int m = 32; m >= 1; m >>= 1) p += __shfl_xor(p, m, 64);
      if (tid == 0) {
        if (g == 0) p += blin + xv;            // bias + residual, added once
        unsafeAtomicAdd(&y[t * BATCH + b], p);
      }
    }
  }
}

extern "C" void kernel_launch(void* const* d_in, const int* in_sizes, int n_in,
                              void* d_out, int out_size, void* d_ws, size_t ws_size,
                              hipStream_t stream) {
  const float* x0    = (const float*)d_in[0];
  const float* W_ih  = (const float*)d_in[1];
  const float* W_hh  = (const float*)d_in[2];
  const float* b_ih  = (const float*)d_in[3];
  const float* b_hh  = (const float*)d_in[4];
  const float* W_lin = (const float*)d_in[5];
  const float* b_lin = (const float*)d_in[6];
  float* y = (float*)d_out;

  uint32_t* h_ex = (uint32_t*)d_ws;   // [2][BATCH][512] u32 = 128 KB
  const size_t init_bytes = 2 * BATCH * 512 * sizeof(uint32_t);

  // h0 = 0 with tag 0 (slot 0): memset-0 IS the correct initial state.
  hipMemsetAsync(d_ws, 0, init_bytes, stream);
  hipMemsetAsync(d_out, 0, (size_t)out_size * sizeof(float), stream);

  hipLaunchKernelGGL(lstm_persistent, dim3(BATCH * GROUPS), dim3(BLK_THREADS),
                     0, stream,
                     x0, W_ih, W_hh, b_ih, b_hh, W_lin, b_lin, y, h_ex);
}